// Round 2
// baseline (94794.061 us; speedup 1.0000x reference)
//
#include <hip/hip_runtime.h>
#include <hip/hip_bf16.h>

// Problem sizes (fixed by the reference)
#define SEQ   8192
#define DIN   1024
#define DH    2048
#define DOUT  1024

#define SENT 0x7fc0deadu  // quiet-NaN payload; tanh output can never equal this

// ---------------------------------------------------------------------------
// Fill hs with sentinel (must run every launch: harness does not re-poison ws)
// ---------------------------------------------------------------------------
__global__ __launch_bounds__(256) void fill_sent_kernel(uint4* __restrict__ p, size_t n4) {
    size_t i = (size_t)blockIdx.x * blockDim.x + threadIdx.x;
    size_t stride = (size_t)gridDim.x * blockDim.x;
    uint4 v = make_uint4(SENT, SENT, SENT, SENT);
    for (; i < n4; i += stride) p[i] = v;
}

// ---------------------------------------------------------------------------
// C[m][n] = bias[n] + sum_k A[m][k] * B[n][k]    (A: MxK, B: NxK, C: MxN)
// 64x64 tile, BK=16, 256 threads, 4x4 per-thread accumulators. fp32.
// ---------------------------------------------------------------------------
__global__ __launch_bounds__(256) void gemm_nt_bias(
    const float* __restrict__ A, const float* __restrict__ B,
    const float* __restrict__ bias, float* __restrict__ C,
    int M, int N, int K) {
    __shared__ float As[16][68];
    __shared__ float Bs[16][68];
    const int tid = threadIdx.x;
    const int bm = blockIdx.x * 64;
    const int bn = blockIdx.y * 64;
    const int lr = tid >> 2;          // 0..63   (tile row for staging loads)
    const int lk = (tid & 3) * 4;     // 0,4,8,12 (k quad)
    const int tm = (tid >> 4) * 4;    // 0..60
    const int tn = (tid & 15) * 4;    // 0..60
    float acc[4][4] = {};

    for (int k0 = 0; k0 < K; k0 += 16) {
        const float4 av = *(const float4*)&A[(size_t)(bm + lr) * K + k0 + lk];
        const float4 bv = *(const float4*)&B[(size_t)(bn + lr) * K + k0 + lk];
        As[lk + 0][lr] = av.x; As[lk + 1][lr] = av.y;
        As[lk + 2][lr] = av.z; As[lk + 3][lr] = av.w;
        Bs[lk + 0][lr] = bv.x; Bs[lk + 1][lr] = bv.y;
        Bs[lk + 2][lr] = bv.z; Bs[lk + 3][lr] = bv.w;
        __syncthreads();
#pragma unroll
        for (int k = 0; k < 16; ++k) {
            const float4 a4 = *(const float4*)&As[k][tm];
            const float4 b4 = *(const float4*)&Bs[k][tn];
            const float a[4] = {a4.x, a4.y, a4.z, a4.w};
            const float b[4] = {b4.x, b4.y, b4.z, b4.w};
#pragma unroll
            for (int i = 0; i < 4; ++i)
#pragma unroll
                for (int j = 0; j < 4; ++j)
                    acc[i][j] = fmaf(a[i], b[j], acc[i][j]);
        }
        __syncthreads();
    }

    const float4 bv = *(const float4*)&bias[bn + tn];
#pragma unroll
    for (int i = 0; i < 4; ++i) {
        float4 o;
        o.x = acc[i][0] + bv.x;
        o.y = acc[i][1] + bv.y;
        o.z = acc[i][2] + bv.z;
        o.w = acc[i][3] + bv.w;
        *(float4*)&C[(size_t)(bm + tm + i) * N + bn + tn] = o;
    }
}

// ---------------------------------------------------------------------------
// Persistent recurrence kernel: 128 WGs x 256 threads = 512 INDEPENDENT waves
// (no LDS, no barriers). Wave g owns rows [4g, 4g+4) of W_hh in VGPRs
// (lane l -> cols {4l+256j+k}). Per step:
//   1) prefetch xw[t] (overlaps poll)
//   2) batch-issue ALL 32 agent-scope poll loads of h[t-1] (one overlapped
//      round trip), then re-poll only words still == sentinel
//   3) 128 FMAs/lane, 7-shuffle select-merge butterfly (row r -> lane r)
//   4) tanh + agent-scope store of this wave's 4 rows (data IS the flag)
// ---------------------------------------------------------------------------
__global__ __launch_bounds__(256, 1) void rnn_recurrence(
    const float* __restrict__ Whh, const float* __restrict__ xw,
    const float* __restrict__ h0, float* __restrict__ hs) {
    const int tid = threadIdx.x;
    const int wave = tid >> 6;
    const int lane = tid & 63;
    const int row0 = blockIdx.x * 16 + wave * 4;  // this wave's first row

    // Load this wave's 4x2048 weight slice into registers (128 VGPRs/lane)
    float4 w4[4][8];
#pragma unroll
    for (int r = 0; r < 4; ++r)
#pragma unroll
        for (int j = 0; j < 8; ++j)
            w4[r][j] = *(const float4*)&Whh[(size_t)(row0 + r) * DH + lane * 4 + 256 * j];

    for (int t = 0; t < SEQ; ++t) {
        // ---- prefetch xw for this wave's rows (issued before the poll) ----
        const float xwv = xw[(size_t)t * DH + row0 + (lane & 3)];

        // ---- h[t-1] into registers, in the exact compute layout ----
        unsigned hv[32];
        if (t == 0) {
#pragma unroll
            for (int j = 0; j < 8; ++j) {
                const float4 h4 = *(const float4*)&h0[lane * 4 + 256 * j];
                hv[j * 4 + 0] = __float_as_uint(h4.x);
                hv[j * 4 + 1] = __float_as_uint(h4.y);
                hv[j * 4 + 2] = __float_as_uint(h4.z);
                hv[j * 4 + 3] = __float_as_uint(h4.w);
            }
        } else {
            const unsigned* src = (const unsigned*)(hs + (size_t)(t - 1) * DH);
            // batch-issue: 32 independent loads, one overlapped round trip
#pragma unroll
            for (int j = 0; j < 8; ++j)
#pragma unroll
                for (int k = 0; k < 4; ++k)
                    hv[j * 4 + k] = __hip_atomic_load(
                        src + lane * 4 + 256 * j + k,
                        __ATOMIC_RELAXED, __HIP_MEMORY_SCOPE_AGENT);
            asm volatile("" ::: "memory");  // keep issue batch ahead of checks
            // fix up stragglers only
#pragma unroll
            for (int j = 0; j < 8; ++j)
#pragma unroll
                for (int k = 0; k < 4; ++k)
                    while (hv[j * 4 + k] == SENT)
                        hv[j * 4 + k] = __hip_atomic_load(
                            src + lane * 4 + 256 * j + k,
                            __ATOMIC_RELAXED, __HIP_MEMORY_SCOPE_AGENT);
        }

        // ---- 4 rows x 32 cols of FMAs per lane ----
        float acc0 = 0.f, acc1 = 0.f, acc2 = 0.f, acc3 = 0.f;
#pragma unroll
        for (int j = 0; j < 8; ++j) {
            const float hx = __uint_as_float(hv[j * 4 + 0]);
            const float hy = __uint_as_float(hv[j * 4 + 1]);
            const float hz = __uint_as_float(hv[j * 4 + 2]);
            const float hw = __uint_as_float(hv[j * 4 + 3]);
            acc0 = fmaf(w4[0][j].x, hx, acc0); acc0 = fmaf(w4[0][j].y, hy, acc0);
            acc0 = fmaf(w4[0][j].z, hz, acc0); acc0 = fmaf(w4[0][j].w, hw, acc0);
            acc1 = fmaf(w4[1][j].x, hx, acc1); acc1 = fmaf(w4[1][j].y, hy, acc1);
            acc1 = fmaf(w4[1][j].z, hz, acc1); acc1 = fmaf(w4[1][j].w, hw, acc1);
            acc2 = fmaf(w4[2][j].x, hx, acc2); acc2 = fmaf(w4[2][j].y, hy, acc2);
            acc2 = fmaf(w4[2][j].z, hz, acc2); acc2 = fmaf(w4[2][j].w, hw, acc2);
            acc3 = fmaf(w4[3][j].x, hx, acc3); acc3 = fmaf(w4[3][j].y, hy, acc3);
            acc3 = fmaf(w4[3][j].z, hz, acc3); acc3 = fmaf(w4[3][j].w, hw, acc3);
        }

        // ---- select-merge butterfly: 7 shuffles, lane l ends with row (l&3) ----
        float a01 = (lane & 1) ? acc1 : acc0;
        float b01 = (lane & 1) ? acc0 : acc1;
        a01 += __shfl_xor(b01, 1);
        float a23 = (lane & 1) ? acc3 : acc2;
        float b23 = (lane & 1) ? acc2 : acc3;
        a23 += __shfl_xor(b23, 1);
        float a = (lane & 2) ? a23 : a01;
        float b = (lane & 2) ? a01 : a23;
        a += __shfl_xor(b, 2);
        a += __shfl_xor(a, 4);
        a += __shfl_xor(a, 8);
        a += __shfl_xor(a, 16);
        a += __shfl_xor(a, 32);

        // ---- tanh + agent-visible store of this wave's 4 rows ----
        if (lane < 4) {
            const float hval = tanhf(a + xwv);
            __hip_atomic_store((unsigned*)(hs + (size_t)t * DH + row0 + lane),
                               __float_as_uint(hval),
                               __ATOMIC_RELAXED, __HIP_MEMORY_SCOPE_AGENT);
        }
    }
}

// ---------------------------------------------------------------------------
// Copy h_final = hs[SEQ-1] into the output tail
// ---------------------------------------------------------------------------
__global__ __launch_bounds__(256) void copy_hfinal(const float* __restrict__ hs,
                                                   float* __restrict__ out) {
    const int i = blockIdx.x * 256 + threadIdx.x;
    out[i] = hs[(size_t)(SEQ - 1) * DH + i];
}

// ---------------------------------------------------------------------------
extern "C" void kernel_launch(void* const* d_in, const int* in_sizes, int n_in,
                              void* d_out, int out_size, void* d_ws, size_t ws_size,
                              hipStream_t stream) {
    (void)in_sizes; (void)n_in; (void)out_size; (void)ws_size;
    const float* x_seq  = (const float*)d_in[0];  // (SEQ, DIN)
    const float* h0     = (const float*)d_in[1];  // (DH,)
    const float* W_ih   = (const float*)d_in[2];  // (DH, DIN)
    const float* W_hh   = (const float*)d_in[3];  // (DH, DH)
    const float* b_h    = (const float*)d_in[4];  // (DH,)
    const float* W_ho_w = (const float*)d_in[5];  // (DOUT, DH)
    const float* W_ho_b = (const float*)d_in[6];  // (DOUT,)
    float* out = (float*)d_out;                   // (SEQ*DOUT) then (DH,)

    float* xw = (float*)d_ws;                     // SEQ*DH fp32 = 64 MB
    float* hs = xw + (size_t)SEQ * DH;            // SEQ*DH fp32 = 64 MB

    // 1) sentinel-fill hs (dataflow flags)
    fill_sent_kernel<<<2048, 256, 0, stream>>>((uint4*)hs, (size_t)SEQ * DH / 4);

    // 2) xw = x_seq @ W_ih.T + b_h
    gemm_nt_bias<<<dim3(SEQ / 64, DH / 64), 256, 0, stream>>>(
        x_seq, W_ih, b_h, xw, SEQ, DH, DIN);

    // 3) sequential recurrence (persistent dataflow kernel, barrier-free)
    rnn_recurrence<<<DH / 16, 256, 0, stream>>>(W_hh, xw, h0, hs);

    // 4) out = hs @ W_ho_w.T + W_ho_b
    gemm_nt_bias<<<dim3(SEQ / 64, DOUT / 64), 256, 0, stream>>>(
        hs, W_ho_w, W_ho_b, out, SEQ, DOUT, DH);

    // 5) h_final
    copy_hfinal<<<DH / 256, 256, 0, stream>>>(hs, out + (size_t)SEQ * DOUT);
}

// Round 4
// 22697.377 us; speedup vs baseline: 4.1764x; 4.1764x over previous
//
#include <hip/hip_runtime.h>
#include <hip/hip_bf16.h>

// Problem sizes (fixed by the reference)
#define SEQ   8192
#define DIN   1024
#define DH    2048
#define DOUT  1024

#define SENT 0x7fc0deadu  // quiet-NaN payload; tanh output can never equal this

// ---------------------------------------------------------------------------
// Fill hs with sentinel (must run every launch: harness does not re-poison ws)
// ---------------------------------------------------------------------------
__global__ __launch_bounds__(256) void fill_sent_kernel(uint4* __restrict__ p, size_t n4) {
    size_t i = (size_t)blockIdx.x * blockDim.x + threadIdx.x;
    size_t stride = (size_t)gridDim.x * blockDim.x;
    uint4 v = make_uint4(SENT, SENT, SENT, SENT);
    for (; i < n4; i += stride) p[i] = v;
}

// ---------------------------------------------------------------------------
// C[m][n] = bias[n] + sum_k A[m][k] * B[n][k]    (A: MxK, B: NxK, C: MxN)
// 64x64 tile, BK=16, 256 threads, 4x4 per-thread accumulators. fp32.
// ---------------------------------------------------------------------------
__global__ __launch_bounds__(256) void gemm_nt_bias(
    const float* __restrict__ A, const float* __restrict__ B,
    const float* __restrict__ bias, float* __restrict__ C,
    int M, int N, int K) {
    __shared__ float As[16][68];
    __shared__ float Bs[16][68];
    const int tid = threadIdx.x;
    const int bm = blockIdx.x * 64;
    const int bn = blockIdx.y * 64;
    const int lr = tid >> 2;          // 0..63   (tile row for staging loads)
    const int lk = (tid & 3) * 4;     // 0,4,8,12 (k quad)
    const int tm = (tid >> 4) * 4;    // 0..60
    const int tn = (tid & 15) * 4;    // 0..60
    float acc[4][4] = {};

    for (int k0 = 0; k0 < K; k0 += 16) {
        const float4 av = *(const float4*)&A[(size_t)(bm + lr) * K + k0 + lk];
        const float4 bv = *(const float4*)&B[(size_t)(bn + lr) * K + k0 + lk];
        As[lk + 0][lr] = av.x; As[lk + 1][lr] = av.y;
        As[lk + 2][lr] = av.z; As[lk + 3][lr] = av.w;
        Bs[lk + 0][lr] = bv.x; Bs[lk + 1][lr] = bv.y;
        Bs[lk + 2][lr] = bv.z; Bs[lk + 3][lr] = bv.w;
        __syncthreads();
#pragma unroll
        for (int k = 0; k < 16; ++k) {
            const float4 a4 = *(const float4*)&As[k][tm];
            const float4 b4 = *(const float4*)&Bs[k][tn];
            const float a[4] = {a4.x, a4.y, a4.z, a4.w};
            const float b[4] = {b4.x, b4.y, b4.z, b4.w};
#pragma unroll
            for (int i = 0; i < 4; ++i)
#pragma unroll
                for (int j = 0; j < 4; ++j)
                    acc[i][j] = fmaf(a[i], b[j], acc[i][j]);
        }
        __syncthreads();
    }

    const float4 bv = *(const float4*)&bias[bn + tn];
#pragma unroll
    for (int i = 0; i < 4; ++i) {
        float4 o;
        o.x = acc[i][0] + bv.x;
        o.y = acc[i][1] + bv.y;
        o.z = acc[i][2] + bv.z;
        o.w = acc[i][3] + bv.w;
        *(float4*)&C[(size_t)(bm + tm + i) * N + bn + tn] = o;
    }
}

// ---------------------------------------------------------------------------
// Persistent recurrence kernel: 128 WGs x 256 threads. WG b owns rows
// [16b, 16b+16) of W_hh, PINNED in VGPRs (per-scalar asm "+v" ties defeat
// rematerialization — R2 showed the compiler otherwise re-loads 32KB/wave/step
// from L2; R3 showed float4 ties don't compile, scalar ties do).
// Per step:
//   1) prefetch xw[t]
//   2) WG-cooperative poll of h[t-1]: 8 words/thread, batch-issued; straggler
//      re-poll is BATCHED per round (mask do-while), not serial per word
//   3) stage into double-buffered LDS (parity t&1) -> ONE barrier per step
//   4) 128 FMAs/lane, 7-shuffle select-merge reduce, tanh, agent store
// ---------------------------------------------------------------------------
__global__ __launch_bounds__(256, 1) void rnn_recurrence(
    const float* __restrict__ Whh, const float* __restrict__ xw,
    const float* __restrict__ h0, float* __restrict__ hs) {
    __shared__ float h_lds[2][DH];
    const int tid = threadIdx.x;
    const int wave = tid >> 6;
    const int lane = tid & 63;
    const int row0 = blockIdx.x * 16 + wave * 4;  // this wave's first row

    // Load this wave's 4x2048 weight slice and PIN it in registers.
    float4 w4[4][8];
#pragma unroll
    for (int r = 0; r < 4; ++r)
#pragma unroll
        for (int j = 0; j < 8; ++j) {
            w4[r][j] = *(const float4*)&Whh[(size_t)(row0 + r) * DH + lane * 4 + 256 * j];
            asm volatile("" : "+v"(w4[r][j].x), "+v"(w4[r][j].y),
                              "+v"(w4[r][j].z), "+v"(w4[r][j].w));
        }

    for (int t = 0; t < SEQ; ++t) {
        const int par = t & 1;
        // ---- prefetch xw for this wave's rows (issued before the poll) ----
        const float xwv = xw[(size_t)t * DH + row0 + (lane & 3)];

        // ---- stage h[t-1] into LDS[par] (cooperative, 8 words/thread) ----
        if (t == 0) {
#pragma unroll
            for (int j = 0; j < 8; ++j)
                h_lds[0][j * 256 + tid] = h0[j * 256 + tid];
        } else {
            const unsigned* src = (const unsigned*)(hs + (size_t)(t - 1) * DH);
            unsigned v[8];
#pragma unroll
            for (int j = 0; j < 8; ++j)
                v[j] = __hip_atomic_load(src + j * 256 + tid, __ATOMIC_RELAXED,
                                         __HIP_MEMORY_SCOPE_AGENT);
            unsigned pend = 0;
#pragma unroll
            for (int j = 0; j < 8; ++j)
                pend |= (v[j] == SENT) ? (1u << j) : 0u;
            while (__builtin_expect(pend != 0, 0)) {
                unsigned nv[8];
#pragma unroll
                for (int j = 0; j < 8; ++j)
                    if (pend & (1u << j))
                        nv[j] = __hip_atomic_load(src + j * 256 + tid,
                                                  __ATOMIC_RELAXED,
                                                  __HIP_MEMORY_SCOPE_AGENT);
#pragma unroll
                for (int j = 0; j < 8; ++j)
                    if ((pend & (1u << j)) && nv[j] != SENT) {
                        v[j] = nv[j];
                        pend &= ~(1u << j);
                    }
            }
#pragma unroll
            for (int j = 0; j < 8; ++j)
                h_lds[par][j * 256 + tid] = __uint_as_float(v[j]);
        }
        __syncthreads();  // single barrier/step (double-buffered LDS)

        // ---- pull h into registers in the compute pattern ----
        float4 h4[8];
#pragma unroll
        for (int j = 0; j < 8; ++j)
            h4[j] = *(const float4*)&h_lds[par][lane * 4 + 256 * j];

        // ---- 4 rows x 32 cols of FMAs per lane ----
        float acc0 = 0.f, acc1 = 0.f, acc2 = 0.f, acc3 = 0.f;
#pragma unroll
        for (int j = 0; j < 8; ++j) {
            const float4 hv = h4[j];
            acc0 = fmaf(w4[0][j].x, hv.x, acc0); acc0 = fmaf(w4[0][j].y, hv.y, acc0);
            acc0 = fmaf(w4[0][j].z, hv.z, acc0); acc0 = fmaf(w4[0][j].w, hv.w, acc0);
            acc1 = fmaf(w4[1][j].x, hv.x, acc1); acc1 = fmaf(w4[1][j].y, hv.y, acc1);
            acc1 = fmaf(w4[1][j].z, hv.z, acc1); acc1 = fmaf(w4[1][j].w, hv.w, acc1);
            acc2 = fmaf(w4[2][j].x, hv.x, acc2); acc2 = fmaf(w4[2][j].y, hv.y, acc2);
            acc2 = fmaf(w4[2][j].z, hv.z, acc2); acc2 = fmaf(w4[2][j].w, hv.w, acc2);
            acc3 = fmaf(w4[3][j].x, hv.x, acc3); acc3 = fmaf(w4[3][j].y, hv.y, acc3);
            acc3 = fmaf(w4[3][j].z, hv.z, acc3); acc3 = fmaf(w4[3][j].w, hv.w, acc3);
        }

        // ---- select-merge butterfly: 7 shuffles, lane l ends with row (l&3) ----
        float a01 = (lane & 1) ? acc1 : acc0;
        float b01 = (lane & 1) ? acc0 : acc1;
        a01 += __shfl_xor(b01, 1);
        float a23 = (lane & 1) ? acc3 : acc2;
        float b23 = (lane & 1) ? acc2 : acc3;
        a23 += __shfl_xor(b23, 1);
        float a = (lane & 2) ? a23 : a01;
        float b = (lane & 2) ? a01 : a23;
        a += __shfl_xor(b, 2);
        a += __shfl_xor(a, 4);
        a += __shfl_xor(a, 8);
        a += __shfl_xor(a, 16);
        a += __shfl_xor(a, 32);

        // ---- tanh + agent-visible store of this wave's 4 rows ----
        if (lane < 4) {
            const float hval = tanhf(a + xwv);
            __hip_atomic_store((unsigned*)(hs + (size_t)t * DH + row0 + lane),
                               __float_as_uint(hval),
                               __ATOMIC_RELAXED, __HIP_MEMORY_SCOPE_AGENT);
        }
    }
}

// ---------------------------------------------------------------------------
// Copy h_final = hs[SEQ-1] into the output tail
// ---------------------------------------------------------------------------
__global__ __launch_bounds__(256) void copy_hfinal(const float* __restrict__ hs,
                                                   float* __restrict__ out) {
    const int i = blockIdx.x * 256 + threadIdx.x;
    out[i] = hs[(size_t)(SEQ - 1) * DH + i];
}

// ---------------------------------------------------------------------------
extern "C" void kernel_launch(void* const* d_in, const int* in_sizes, int n_in,
                              void* d_out, int out_size, void* d_ws, size_t ws_size,
                              hipStream_t stream) {
    (void)in_sizes; (void)n_in; (void)out_size; (void)ws_size;
    const float* x_seq  = (const float*)d_in[0];  // (SEQ, DIN)
    const float* h0     = (const float*)d_in[1];  // (DH,)
    const float* W_ih   = (const float*)d_in[2];  // (DH, DIN)
    const float* W_hh   = (const float*)d_in[3];  // (DH, DH)
    const float* b_h    = (const float*)d_in[4];  // (DH,)
    const float* W_ho_w = (const float*)d_in[5];  // (DOUT, DH)
    const float* W_ho_b = (const float*)d_in[6];  // (DOUT,)
    float* out = (float*)d_out;                   // (SEQ*DOUT) then (DH,)

    float* xw = (float*)d_ws;                     // SEQ*DH fp32 = 64 MB
    float* hs = xw + (size_t)SEQ * DH;            // SEQ*DH fp32 = 64 MB

    // 1) sentinel-fill hs (dataflow flags)
    fill_sent_kernel<<<2048, 256, 0, stream>>>((uint4*)hs, (size_t)SEQ * DH / 4);

    // 2) xw = x_seq @ W_ih.T + b_h
    gemm_nt_bias<<<dim3(SEQ / 64, DH / 64), 256, 0, stream>>>(
        x_seq, W_ih, b_h, xw, SEQ, DH, DIN);

    // 3) sequential recurrence (persistent dataflow kernel)
    rnn_recurrence<<<DH / 16, 256, 0, stream>>>(W_hh, xw, h0, hs);

    // 4) out = hs @ W_ho_w.T + W_ho_b
    gemm_nt_bias<<<dim3(SEQ / 64, DOUT / 64), 256, 0, stream>>>(
        hs, W_ho_w, W_ho_b, out, SEQ, DOUT, DH);

    // 5) h_final
    copy_hfinal<<<DH / 256, 256, 0, stream>>>(hs, out + (size_t)SEQ * DOUT);
}